// Round 9
// baseline (468.017 us; speedup 1.0000x reference)
//
#include <hip/hip_runtime.h>
#include <cstddef>

// Swin shifted-window attention, fused per-window MFMA kernel, fp16, v9.
// v8 + registers-first dataflow:
//  - q: wave w computes its own m-tile's q (6 weight tiles, dbuf), D-words stay in
//    regs; qa B-frags built via ds_bpermute (2 bperm + 1 sel per word). QT LDS gone.
//  - ao: PV D-frags -> ob B-frags via the same bpermute; no LDS round-trip, no
//    phase-3 LDS reads. (Transpose algebra == v8's verified LDS swizzle path.)
//  - P: v8's LDS write->read kept, relocated to a 2KB/wave pool.
//  - k/v: wave owns 3 n-tiles with weights register-resident; m-outer loop with
//    xb prefetch.
// LDS = KT 12K + VT 12K + PP 8K = 32768 B exactly -> 5 blocks/CU (20 waves/CU).
// One barrier total.

typedef _Float16 half8 __attribute__((ext_vector_type(8)));
typedef float f4v __attribute__((ext_vector_type(4)));
typedef unsigned short u16;
typedef unsigned int u32;

#define MFMA(A, B, C) __builtin_amdgcn_mfma_f32_16x16x32_f16((A), (B), (C), 0, 0, 0)
#define BPERM(addr, val) __builtin_amdgcn_ds_bpermute((addr), (val))

__device__ inline u16 f16b(float f) { return __builtin_bit_cast(u16, (_Float16)f); }
__device__ inline u32 pkrtz(float a, float b) {
    return __builtin_bit_cast(u32, __builtin_amdgcn_cvt_pkrtz(a, b));
}
// fragment-LDS unit swizzle: byte = frag*1024 + unit*16 + elem*2
__device__ inline int SWU(int a, int kg) {
    return (((a ^ (kg << 1) ^ ((a & 8) >> 1)) & 15) | (kg << 4));
}

// ---- prep: weights -> f16 (q pre-scaled by SCALE*log2e); bias -> C-fragment layout ----
__global__ void prep_kernel(const float* __restrict__ wqkv, const float* __restrict__ wout,
                            const float* __restrict__ btab, const int* __restrict__ ridx,
                            const float* __restrict__ bqkv,
                            u16* __restrict__ wq16, u16* __restrict__ wo16,
                            float* __restrict__ bmf, float* __restrict__ bqs)
{
    const int i = blockIdx.x * 256 + threadIdx.x;
    const float LOG2E = 1.4426950408889634f;
    const float QS = 0.17677669529663688f * LOG2E;   // 1/sqrt(32) * log2(e)
    if (i < 27648) {
        float f = wqkv[i];
        if (i < 9216) f *= QS;                 // q rows
        wq16[i] = f16b(f);
    } else if (i < 36864) {
        wo16[i - 27648] = f16b(wout[i - 27648]);
    } else if (i < 49152) {
        // bmf: C-operand fragments, j = ((h*4+ut)*4+w)*256 + lane*4 + i
        // lane (l15,lg), reg i holds D[u = ut*16+lg*4+i][t = w*16+l15]
        const int j  = i - 36864;
        const int fi = j & 3, ln = (j >> 2) & 63, fw = (j >> 8) & 3;
        const int fut = (j >> 10) & 3, fh = j >> 12;
        const int u  = fut * 16 + (ln >> 4) * 4 + fi;
        const int tt = fw * 16 + (ln & 15);
        float v;
        if (u >= 49)       v = -1e30f;                                  // mask baked in
        else if (tt >= 49) v = 0.f;                                     // junk rows, don't care
        else               v = btab[ridx[tt * 49 + u] * 3 + fh] * LOG2E;
        bmf[j] = v;
    } else if (i < 49440) {
        const int j = i - 49152;
        float f = bqkv[j];
        if (j < 96) f *= QS;
        bqs[j] = f;
    }
}

// ---- main fused kernel ----
__global__ __launch_bounds__(256, 5)
void swin_kernel(const float* __restrict__ x,
                 const u16* __restrict__ wq16,
                 const u16* __restrict__ wo16,
                 const float* __restrict__ bqs,
                 const float* __restrict__ bout,
                 const float* __restrict__ bmf,
                 float* __restrict__ out)
{
    // LDS map (32768 B exactly -> 5 blocks/CU):
    //   KT [0,12288)       kt frag(h*4+ut)         (shared, read-only after barrier)
    //   VT [12288,24576)   vt frag((h*2+nd)*2+ku)  (shared, read-only after barrier)
    //   PP [24576,32768)   P pool, 2 KB per wave (wave-private: ku0 at +0, ku1 at +1024)
    __shared__ __attribute__((aligned(16))) char smem[32768];
    constexpr int KT = 0, VT = 12288, PP = 24576;

    const int tid  = threadIdx.x;
    const int w    = tid >> 6;        // wave 0..3 = token m-tile owned
    const int lane = tid & 63;
    const int l15  = lane & 15;
    const int lg   = lane >> 4;       // 0..3

    const int blk = blockIdx.x;
    const int bb  = blk >> 10;
    const int wi7 = ((blk >> 5) & 31) * 7;
    const int wj7 = (blk & 31) * 7;

    const int swbase = SWU(l15, lg) * 16;
    const int elb    = (lg & 1) * 8;          // byte offset of elem block within unit

    // pixel offset (floats) for token t of this window, shifted
    auto pixoff = [&](int t) -> size_t {
        const int tr = t / 7, tc = t - tr * 7;
        int r = wi7 + tr + 3; if (r >= 224) r -= 224;
        int c = wj7 + tc + 3; if (c >= 224) c -= 224;
        return ((size_t)((bb * 224 + r) * 224 + c)) * 96;
    };
    // load X^T B-frag (3 half8) for token row t, k-chunk lg*8
    auto loadxb = [&](int t, half8* dst) {
        const float* xrow = x + pixoff(t) + lg * 8;
        #pragma unroll
        for (int ks = 0; ks < 3; ++ks) {
            const float4 f0 = *(const float4*)(xrow + ks * 32);
            const float4 f1 = *(const float4*)(xrow + ks * 32 + 4);
            uint4 pk;
            pk.x = pkrtz(f0.x, f0.y); pk.y = pkrtz(f0.z, f0.w);
            pk.z = pkrtz(f1.x, f1.y); pk.w = pkrtz(f1.z, f1.w);
            dst[ks] = __builtin_bit_cast(half8, pk);
        }
    };

    // ============ Phase 1a: q projection for own m-tile (m = w) ============
    u32 qd[12];                               // D-words: qd[2n+word], n = 0..5
    {
        half8 xbw[3];
        loadxb(w * 16 + l15, xbw);
        const u16* wbase = wq16 + (size_t)l15 * 96 + lg * 8;
        half8 bcur[3], bnxt[3];
        bcur[0] = *(const half8*)(wbase);
        bcur[1] = *(const half8*)(wbase + 32);
        bcur[2] = *(const half8*)(wbase + 64);
        #pragma unroll
        for (int n = 0; n < 6; ++n) {
            if (n < 5) {
                const u16* p = wbase + (n + 1) * 1536;
                bnxt[0] = *(const half8*)(p);
                bnxt[1] = *(const half8*)(p + 32);
                bnxt[2] = *(const half8*)(p + 64);
            }
            f4v acc = {0.f, 0.f, 0.f, 0.f};
            acc = MFMA(bcur[0], xbw[0], acc);
            acc = MFMA(bcur[1], xbw[1], acc);
            acc = MFMA(bcur[2], xbw[2], acc);
            const float4 b4 = *(const float4*)(bqs + n * 16 + lg * 4);
            qd[2 * n]     = pkrtz(acc[0] + b4.x, acc[1] + b4.y);
            qd[2 * n + 1] = pkrtz(acc[2] + b4.z, acc[3] + b4.w);
            if (n < 5) { bcur[0] = bnxt[0]; bcur[1] = bnxt[1]; bcur[2] = bnxt[2]; }
        }
    }

    // ============ Phase 1b: k/v projection, wave owns n in {6+w, 10+w, 14+w} ============
    {
        half8 kvw[3][3];                      // 3 weight tiles register-resident
        #pragma unroll
        for (int i = 0; i < 3; ++i) {
            const u16* p = wq16 + (size_t)(6 + w + 4 * i) * 1536 + (size_t)l15 * 96 + lg * 8;
            kvw[i][0] = *(const half8*)(p);
            kvw[i][1] = *(const half8*)(p + 32);
            kvw[i][2] = *(const half8*)(p + 64);
        }
        half8 xc[3], xn[3];
        loadxb(l15, xc);                      // m = 0
        #pragma unroll
        for (int m = 0; m < 4; ++m) {
            if (m < 3) loadxb((m + 1) * 16 + l15, xn);
            #pragma unroll
            for (int i = 0; i < 3; ++i) {
                const int n = 6 + w + 4 * i;  // uniform per wave
                if (n < 12) {                 // k: transposed (A=W, B=X^T)
                    f4v acc = {0.f, 0.f, 0.f, 0.f};
                    acc = MFMA(kvw[i][0], xc[0], acc);
                    acc = MFMA(kvw[i][1], xc[1], acc);
                    acc = MFMA(kvw[i][2], xc[2], acc);
                    const float4 b4 = *(const float4*)(bqs + n * 16 + lg * 4);
                    uint2 pv;
                    pv.x = pkrtz(acc[0] + b4.x, acc[1] + b4.y);
                    pv.y = pkrtz(acc[2] + b4.z, acc[3] + b4.w);
                    const int kg  = ((n & 1) << 1) + (lg >> 1);
                    const int fr0 = KT + ((((n - 6) >> 1) * 4) << 10);
                    *(uint2*)(smem + fr0 + (m << 10) + SWU(l15, kg) * 16 + elb) = pv;
                } else {                      // v: direct (A=X, B=W^T)
                    f4v acc = {0.f, 0.f, 0.f, 0.f};
                    acc = MFMA(xc[0], kvw[i][0], acc);
                    acc = MFMA(xc[1], kvw[i][1], acc);
                    acc = MFMA(xc[2], kvw[i][2], acc);
                    const float bv = bqs[n * 16 + l15];
                    uint2 pv;
                    pv.x = pkrtz(acc[0] + bv, acc[1] + bv);
                    pv.y = pkrtz(acc[2] + bv, acc[3] + bv);
                    const int hh = (n - 12) >> 1, nd = n & 1;
                    const int kg = ((m & 1) << 1) + (lg >> 1);
                    *(uint2*)(smem + VT + ((((hh * 2 + nd) * 2) + (m >> 1)) << 10) +
                              SWU(l15, kg) * 16 + elb) = pv;
                }
            }
            if (m < 3) { xc[0] = xn[0]; xc[1] = xn[1]; xc[2] = xn[2]; }
        }
    }

    // ---- build qa[3] B-frags from qd via bpermute (before barrier: reg/DS only) ----
    const int sl0 = (l15 + 16 * ((lg & 1) * 2)) << 2;
    const int sl1 = sl0 + (16 << 2);
    const bool hi = (lg >= 2);
    half8 qa[3];
    #pragma unroll
    for (int h = 0; h < 3; ++h) {
        const int A0 = BPERM(sl0, (int)qd[4 * h + 0]), B0 = BPERM(sl0, (int)qd[4 * h + 2]);
        const int A1 = BPERM(sl0, (int)qd[4 * h + 1]), B1 = BPERM(sl0, (int)qd[4 * h + 3]);
        const int A2 = BPERM(sl1, (int)qd[4 * h + 0]), B2 = BPERM(sl1, (int)qd[4 * h + 2]);
        const int A3 = BPERM(sl1, (int)qd[4 * h + 1]), B3 = BPERM(sl1, (int)qd[4 * h + 3]);
        uint4 qw;
        qw.x = (u32)(hi ? B0 : A0);
        qw.y = (u32)(hi ? B1 : A1);
        qw.z = (u32)(hi ? B2 : A2);
        qw.w = (u32)(hi ? B3 : A3);
        qa[h] = __builtin_bit_cast(half8, qw);
    }
    __syncthreads();      // the ONLY barrier

    // ============ Phase 2: attention (exp2 domain), zero barriers ============
    uint4 obw[3];         // ob B-frags (phase-3 operands), built per head
    {
        const int ppb = PP + (w << 11);
        half8 kb[4]; f4v bC[4];
        #pragma unroll
        for (int ut = 0; ut < 4; ++ut)
            kb[ut] = *(const half8*)(smem + KT + (ut << 10) + swbase);
        {
            const float* bp = bmf + w * 256 + lane * 4;
            #pragma unroll
            for (int ut = 0; ut < 4; ++ut) bC[ut] = *(const f4v*)(bp + ut * 1024);
        }
        #pragma unroll
        for (int h = 0; h < 3; ++h) {
            // scores (bias + u>=49 mask folded into C operand)
            f4v s[4];
            #pragma unroll
            for (int ut = 0; ut < 4; ++ut)
                s[ut] = MFMA(kb[ut], qa[h], bC[ut]);
            // prefetch next head's kb + bC (current ones are dead now)
            if (h < 2) {
                #pragma unroll
                for (int ut = 0; ut < 4; ++ut)
                    kb[ut] = *(const half8*)(smem + KT + (((h + 1) * 4 + ut) << 10) + swbase);
                const float* bp = bmf + (h + 1) * 4096 + w * 256 + lane * 4;
                #pragma unroll
                for (int ut = 0; ut < 4; ++ut) bC[ut] = *(const f4v*)(bp + ut * 1024);
            }
            // softmax over row t (16 vals/lane x 4 lane-groups)
            float mx = -1e30f;
            #pragma unroll
            for (int ut = 0; ut < 4; ++ut)
                #pragma unroll
                for (int i = 0; i < 4; ++i) mx = fmaxf(mx, s[ut][i]);
            mx = fmaxf(mx, __shfl_xor(mx, 16));
            mx = fmaxf(mx, __shfl_xor(mx, 32));
            float sm = 0.f;
            #pragma unroll
            for (int ut = 0; ut < 4; ++ut)
                #pragma unroll
                for (int i = 0; i < 4; ++i) {
                    const float e = exp2f(s[ut][i] - mx);
                    s[ut][i] = e; sm += e;
                }
            sm += __shfl_xor(sm, 16);
            sm += __shfl_xor(sm, 32);
            const float inv = 1.f / sm;
            // P -> LDS pool (b64 swizzled writes), wave-private
            #pragma unroll
            for (int ut = 0; ut < 4; ++ut) {
                uint2 pv;
                pv.x = pkrtz(s[ut][0] * inv, s[ut][1] * inv);
                pv.y = pkrtz(s[ut][2] * inv, s[ut][3] * inv);
                const int kg = (ut & 1) * 2 + (lg >> 1);
                const int base = (ut < 2) ? ppb : (ppb + 1024);
                *(uint2*)(smem + base + SWU(l15, kg) * 16 + elb) = pv;
            }
            // V frag reads + P readback (same-wave DS ordering)
            const half8 vb00 = *(const half8*)(smem + VT + (((h * 2 + 0) * 2 + 0) << 10) + swbase);
            const half8 vb01 = *(const half8*)(smem + VT + (((h * 2 + 0) * 2 + 1) << 10) + swbase);
            const half8 vb10 = *(const half8*)(smem + VT + (((h * 2 + 1) * 2 + 0) << 10) + swbase);
            const half8 vb11 = *(const half8*)(smem + VT + (((h * 2 + 1) * 2 + 1) << 10) + swbase);
            const half8 p0 = *(const half8*)(smem + ppb + swbase);
            const half8 p1 = *(const half8*)(smem + ppb + 1024 + swbase);
            // PV
            u32 aw[4];
            #pragma unroll
            for (int nd = 0; nd < 2; ++nd) {
                f4v o = {0.f, 0.f, 0.f, 0.f};
                o = MFMA(nd ? vb10 : vb00, p0, o);
                o = MFMA(nd ? vb11 : vb01, p1, o);
                aw[nd * 2]     = pkrtz(o[0], o[1]);
                aw[nd * 2 + 1] = pkrtz(o[2], o[3]);
            }
            // ao D-frag -> ob B-frag via bpermute (no LDS)
            {
                const int A0 = BPERM(sl0, (int)aw[0]), B0 = BPERM(sl0, (int)aw[2]);
                const int A1 = BPERM(sl0, (int)aw[1]), B1 = BPERM(sl0, (int)aw[3]);
                const int A2 = BPERM(sl1, (int)aw[0]), B2 = BPERM(sl1, (int)aw[2]);
                const int A3 = BPERM(sl1, (int)aw[1]), B3 = BPERM(sl1, (int)aw[3]);
                obw[h].x = (u32)(hi ? B0 : A0);
                obw[h].y = (u32)(hi ? B1 : A1);
                obw[h].z = (u32)(hi ? B2 : A2);
                obw[h].w = (u32)(hi ? B3 : A3);
            }
        }
    }

    // ============ Phase 3: transposed out-proj (Wo * O^T), ob from registers ============
    {
        const half8 ob0 = __builtin_bit_cast(half8, obw[0]);
        const half8 ob1 = __builtin_bit_cast(half8, obw[1]);
        const half8 ob2 = __builtin_bit_cast(half8, obw[2]);
        const int t = w * 16 + l15;
        float* obase = nullptr;
        if (t < 49) obase = out + pixoff(t);
        #pragma unroll
        for (int nn = 0; nn < 6; ++nn) {
            const u16* wp = wo16 + (size_t)(nn * 16 + l15) * 96 + lg * 8;
            f4v acc = {0.f, 0.f, 0.f, 0.f};
            acc = MFMA(*(const half8*)(wp),      ob0, acc);
            acc = MFMA(*(const half8*)(wp + 32), ob1, acc);
            acc = MFMA(*(const half8*)(wp + 64), ob2, acc);
            if (obase) {
                const float4 bo = *(const float4*)(bout + nn * 16 + lg * 4);
                float4 res;
                res.x = acc[0] + bo.x; res.y = acc[1] + bo.y;
                res.z = acc[2] + bo.z; res.w = acc[3] + bo.w;
                *(float4*)(obase + nn * 16 + lg * 4) = res;
            }
        }
    }
}

extern "C" void kernel_launch(void* const* d_in, const int* in_sizes, int n_in,
                              void* d_out, int out_size, void* d_ws, size_t ws_size,
                              hipStream_t stream) {
    const float* x          = (const float*)d_in[0];
    const float* w_qkv      = (const float*)d_in[1];
    const float* b_qkv      = (const float*)d_in[2];
    const float* w_out      = (const float*)d_in[3];
    const float* b_out      = (const float*)d_in[4];
    const float* bias_table = (const float*)d_in[5];
    const int*   rel_index  = (const int*)d_in[6];
    float* outp = (float*)d_out;

    // d_ws: wq16[27648]u16 | wo16[9216]u16 | bmf[3*4*4*256]f32 | bqs[288]f32  (124032 B)
    u16* wq16 = (u16*)d_ws;
    u16* wo16 = wq16 + 27648;
    float* bmf = (float*)((char*)d_ws + 73728);
    float* bqs = (float*)((char*)d_ws + 122880);

    prep_kernel<<<dim3(194), dim3(256), 0, stream>>>(
        w_qkv, w_out, bias_table, rel_index, b_qkv, wq16, wo16, bmf, bqs);
    swin_kernel<<<dim3(8192), dim3(256), 0, stream>>>(
        x, wq16, wo16, bqs, b_out, bmf, outp);
}

// Round 10
// 202.990 us; speedup vs baseline: 2.3056x; 2.3056x over previous
//
#include <hip/hip_runtime.h>
#include <cstddef>

// Swin shifted-window attention, fused per-window MFMA kernel, fp16, v10.
// = v8 (proven 209us) + low-risk latency/VALU cuts, keeping launch_bounds(256,4):
//  1. ring-3 weight prefetch in phase 1 (statically unrolled n-loop, slot i%3)
//  2. biases folded into MFMA C-operand (phase-1 q/k/v and phase-3), biases
//     preloaded at kernel top into statically-named regs (no dynamic indexing)
//  3. V-fragment LDS reads hoisted before softmax (hide DS latency under VALU)
//  4. phase-3 Wo weights + bias double-buffered (prefetch nn+1 during nn)
// 8192 windows, one per 256-thread block (4 waves); LDS 40960 B -> 4 blocks/CU.
// One barrier total.

typedef _Float16 half8 __attribute__((ext_vector_type(8)));
typedef float f4v __attribute__((ext_vector_type(4)));
typedef unsigned short u16;
typedef unsigned int u32;

#define MFMA(A, B, C) __builtin_amdgcn_mfma_f32_16x16x32_f16((A), (B), (C), 0, 0, 0)

__device__ inline u16 f16b(float f) { return __builtin_bit_cast(u16, (_Float16)f); }
__device__ inline u32 pkrtz(float a, float b) {
    return __builtin_bit_cast(u32, __builtin_amdgcn_cvt_pkrtz(a, b));
}
// fragment-LDS unit swizzle: byte = frag*1024 + unit*16 + elem*2
__device__ inline int SWU(int a, int kg) {
    return (((a ^ (kg << 1) ^ ((a & 8) >> 1)) & 15) | (kg << 4));
}

// ---- prep: weights -> f16 (q pre-scaled by SCALE*log2e); bias -> C-fragment layout ----
__global__ void prep_kernel(const float* __restrict__ wqkv, const float* __restrict__ wout,
                            const float* __restrict__ btab, const int* __restrict__ ridx,
                            const float* __restrict__ bqkv,
                            u16* __restrict__ wq16, u16* __restrict__ wo16,
                            float* __restrict__ bmf, float* __restrict__ bqs)
{
    const int i = blockIdx.x * 256 + threadIdx.x;
    const float LOG2E = 1.4426950408889634f;
    const float QS = 0.17677669529663688f * LOG2E;   // 1/sqrt(32) * log2(e)
    if (i < 27648) {
        float f = wqkv[i];
        if (i < 9216) f *= QS;                 // q rows
        wq16[i] = f16b(f);
    } else if (i < 36864) {
        wo16[i - 27648] = f16b(wout[i - 27648]);
    } else if (i < 49152) {
        // bmf: C-operand fragments, j = ((h*4+ut)*4+w)*256 + lane*4 + i
        // lane (l15,lg), reg i holds D[u = ut*16+lg*4+i][t = w*16+l15]
        const int j  = i - 36864;
        const int fi = j & 3, ln = (j >> 2) & 63, fw = (j >> 8) & 3;
        const int fut = (j >> 10) & 3, fh = j >> 12;
        const int u  = fut * 16 + (ln >> 4) * 4 + fi;
        const int tt = fw * 16 + (ln & 15);
        float v;
        if (u >= 49)       v = -1e30f;                                  // mask baked in
        else if (tt >= 49) v = 0.f;                                     // junk rows, don't care
        else               v = btab[ridx[tt * 49 + u] * 3 + fh] * LOG2E;
        bmf[j] = v;
    } else if (i < 49440) {
        const int j = i - 49152;
        float f = bqkv[j];
        if (j < 96) f *= QS;
        bqs[j] = f;
    }
}

// ---- main fused kernel ----
__global__ __launch_bounds__(256, 4)
void swin_kernel(const float* __restrict__ x,
                 const u16* __restrict__ wq16,
                 const u16* __restrict__ wo16,
                 const float* __restrict__ bqs,
                 const float* __restrict__ bout,
                 const float* __restrict__ bmf,
                 float* __restrict__ out)
{
    // LDS map (40960 B -> 4 blocks/CU):
    //   QT [0,12288)      qt frag(h*4+m); per head: P-ku0 then ao (wave-private in slot [.][w])
    //   KT [12288,24576)  kt frag(h*4+ut)  (read-only after barrier)
    //   VT [24576,36864)  vt frag((h*2+nd)*2+ku)  (read-only after barrier)
    //   PL [36864,40960)  P-ku1, 1KB per wave (wave-private)
    __shared__ __attribute__((aligned(16))) char smem[40960];
    constexpr int QT = 0, KT = 12288, VT = 24576, PL = 36864;

    const int tid  = threadIdx.x;
    const int w    = tid >> 6;        // wave 0..3 = token m-tile owned
    const int lane = tid & 63;
    const int l15  = lane & 15;
    const int lg   = lane >> 4;       // 0..3

    const int blk = blockIdx.x;
    const int bb  = blk >> 10;
    const int wi7 = ((blk >> 5) & 31) * 7;
    const int wj7 = (blk & 31) * 7;

    const int swbase = SWU(l15, lg) * 16;
    const int elb    = (lg & 1) * 8;          // byte offset of elem block within unit

    // ============ Phase 1: QKV projection ============
    // X^T B-frags (dual-use as A-frags for the V path) for all 4 m-tiles.
    half8 xb[4][3];
    #pragma unroll
    for (int m = 0; m < 4; ++m) {
        const int t = m * 16 + l15;           // t>=49 reads junk (wrapped, in-bounds); masked later
        const int tr = t / 7, tc = t - tr * 7;
        int r = wi7 + tr + 3; if (r >= 224) r -= 224;
        int c = wj7 + tc + 3; if (c >= 224) c -= 224;
        const float* xrow = x + ((size_t)((bb * 224 + r) * 224 + c)) * 96 + lg * 8;
        #pragma unroll
        for (int ks = 0; ks < 3; ++ks) {
            const float4 f0 = *(const float4*)(xrow + ks * 32);
            const float4 f1 = *(const float4*)(xrow + ks * 32 + 4);
            uint4 pk;
            pk.x = pkrtz(f0.x, f0.y); pk.y = pkrtz(f0.z, f0.w);
            pk.z = pkrtz(f1.x, f1.y); pk.w = pkrtz(f1.z, f1.w);
            xb[m][ks] = __builtin_bit_cast(half8, pk);
        }
    }
    {
        const u16* wbase = wq16 + (size_t)l15 * 96 + lg * 8;
        // preloaded biases for this wave's n-sequence {w, w+4, w+8, w+12, (w+16 if w<2)}
        const float4 bqA = *(const float4*)(bqs + (w)     * 16 + lg * 4);
        const float4 bqB = *(const float4*)(bqs + (w + 4) * 16 + lg * 4);
        const float4 bqC = *(const float4*)(bqs + (w + 8) * 16 + lg * 4);
        const float  bvA = bqs[(w + 12) * 16 + l15];
        const float  bvB = (w < 2) ? bqs[(w + 16) * 16 + l15] : 0.f;
        // ring-3 weight prefetch
        half8 wr0[3], wr1[3], wr2[3];
        {
            const u16* p = wbase + (size_t)(w) * 1536;
            wr0[0] = *(const half8*)(p); wr0[1] = *(const half8*)(p + 32); wr0[2] = *(const half8*)(p + 64);
        }
        {
            const u16* p = wbase + (size_t)(w + 4) * 1536;
            wr1[0] = *(const half8*)(p); wr1[1] = *(const half8*)(p + 32); wr1[2] = *(const half8*)(p + 64);
        }
        {
            const u16* p = wbase + (size_t)(w + 8) * 1536;
            wr2[0] = *(const half8*)(p); wr2[1] = *(const half8*)(p + 32); wr2[2] = *(const half8*)(p + 64);
        }
        #pragma unroll
        for (int i = 0; i < 5; ++i) {
            const int n = w + 4 * i;          // wave-uniform
            if (i == 4 && w >= 2) break;      // n >= 18
            half8* wcur = (i % 3 == 0) ? wr0 : (i % 3 == 1) ? wr1 : wr2;
            if (i < 3) {                      // q (n<6) or k: transposed (A=W, B=X^T)
                const float4 b4 = (i == 0) ? bqA : (i == 1) ? bqB : bqC;
                const int kg = ((n & 1) << 1) + (lg >> 1);
                const int fr0 = (n < 6) ? (QT + (((n >> 1) * 4) << 10))
                                        : (KT + ((((n - 6) >> 1) * 4) << 10));
                #pragma unroll
                for (int m = 0; m < 4; ++m) {
                    f4v acc = { b4.x, b4.y, b4.z, b4.w };   // bias as C-operand
                    acc = MFMA(wcur[0], xb[m][0], acc);
                    acc = MFMA(wcur[1], xb[m][1], acc);
                    acc = MFMA(wcur[2], xb[m][2], acc);
                    uint2 pv;
                    pv.x = pkrtz(acc[0], acc[1]);
                    pv.y = pkrtz(acc[2], acc[3]);
                    *(uint2*)(smem + fr0 + (m << 10) + SWU(l15, kg) * 16 + elb) = pv;
                }
            } else {                          // v: direct (A=X, B=W^T)
                const float bv = (i == 3) ? bvA : bvB;
                const int hh = (n - 12) >> 1, nd = n & 1;
                const int fr0 = VT + (((hh * 2 + nd) * 2) << 10);
                #pragma unroll
                for (int m = 0; m < 4; ++m) {
                    f4v acc = { bv, bv, bv, bv };           // bias as C-operand
                    acc = MFMA(xb[m][0], wcur[0], acc);
                    acc = MFMA(xb[m][1], wcur[1], acc);
                    acc = MFMA(xb[m][2], wcur[2], acc);
                    uint2 pv;
                    pv.x = pkrtz(acc[0], acc[1]);
                    pv.y = pkrtz(acc[2], acc[3]);
                    const int kg = ((m & 1) << 1) + (lg >> 1);
                    *(uint2*)(smem + fr0 + ((m >> 1) << 10) + SWU(l15, kg) * 16 + elb) = pv;
                }
            }
            // refill consumed ring slot with weights for n+12 (used at iteration i+3)
            if (i == 0 || (i == 1 && w < 2)) {
                const u16* p = wbase + (size_t)(n + 12) * 1536;
                wcur[0] = *(const half8*)(p);
                wcur[1] = *(const half8*)(p + 32);
                wcur[2] = *(const half8*)(p + 64);
            }
        }
    }
    __syncthreads();      // the ONLY barrier

    // ============ Phase 2: attention, software-pipelined, zero barriers ============
    {
        const int plb = PL + (w << 10);
        half8 qaC, qaN;
        half8 kb[2][4];
        f4v   s[2][4];
        f4v   bC[4];

        // preamble: head 0
        qaC = *(const half8*)(smem + QT + ((0 * 4 + w) << 10) + swbase);
        #pragma unroll
        for (int ut = 0; ut < 4; ++ut)
            kb[0][ut] = *(const half8*)(smem + KT + ((0 * 4 + ut) << 10) + swbase);
        {
            const float* bb0 = bmf + w * 256 + lane * 4;
            #pragma unroll
            for (int ut = 0; ut < 4; ++ut) bC[ut] = *(const f4v*)(bb0 + ut * 1024);
        }
        #pragma unroll
        for (int ut = 0; ut < 4; ++ut)
            s[0][ut] = MFMA(kb[0][ut], qaC, bC[ut]);     // bias+mask folded into C

        #pragma unroll
        for (int h = 0; h < 3; ++h) {
            const int cur = h & 1, nxt = cur ^ 1;
            const int qfr = QT + ((h * 4 + w) << 10);
            // prefetch next head operands (DS + global, in flight under softmax)
            if (h < 2) {
                qaN = *(const half8*)(smem + QT + (((h + 1) * 4 + w) << 10) + swbase);
                #pragma unroll
                for (int ut = 0; ut < 4; ++ut)
                    kb[nxt][ut] = *(const half8*)(smem + KT + (((h + 1) * 4 + ut) << 10) + swbase);
                const float* bbn = bmf + (h + 1) * 4096 + w * 256 + lane * 4;
                #pragma unroll
                for (int ut = 0; ut < 4; ++ut) bC[ut] = *(const f4v*)(bbn + ut * 1024);
            }
            // V-frag reads issued EARLY: latency hides under softmax VALU
            const half8 vb00 = *(const half8*)(smem + VT + (((h * 2 + 0) * 2 + 0) << 10) + swbase);
            const half8 vb01 = *(const half8*)(smem + VT + (((h * 2 + 0) * 2 + 1) << 10) + swbase);
            const half8 vb10 = *(const half8*)(smem + VT + (((h * 2 + 1) * 2 + 0) << 10) + swbase);
            const half8 vb11 = *(const half8*)(smem + VT + (((h * 2 + 1) * 2 + 1) << 10) + swbase);
            // softmax on s[cur] (log2 domain; mask already applied via C)
            float mx = fmaxf(fmaxf(s[cur][0][0], s[cur][0][1]), fmaxf(s[cur][0][2], s[cur][0][3]));
            #pragma unroll
            for (int ut = 1; ut < 4; ++ut) {
                mx = fmaxf(mx, fmaxf(fmaxf(s[cur][ut][0], s[cur][ut][1]),
                                     fmaxf(s[cur][ut][2], s[cur][ut][3])));
            }
            mx = fmaxf(mx, __shfl_xor(mx, 16));
            mx = fmaxf(mx, __shfl_xor(mx, 32));
            float sm = 0.f;
            #pragma unroll
            for (int ut = 0; ut < 4; ++ut)
                #pragma unroll
                for (int i = 0; i < 4; ++i) {
                    const float e = exp2f(s[cur][ut][i] - mx);
                    s[cur][ut][i] = e; sm += e;
                }
            sm += __shfl_xor(sm, 16);
            sm += __shfl_xor(sm, 32);
            const float inv = 1.f / sm;
            // pack + write P (ku0 -> qt[h][w] slot, ku1 -> PL[w]; both wave-private)
            #pragma unroll
            for (int ut = 0; ut < 4; ++ut) {
                uint2 pv;
                pv.x = pkrtz(s[cur][ut][0] * inv, s[cur][ut][1] * inv);
                pv.y = pkrtz(s[cur][ut][2] * inv, s[cur][ut][3] * inv);
                const int kg = (ut & 1) * 2 + (lg >> 1);
                const int base = (ut < 2) ? qfr : plb;
                *(uint2*)(smem + base + SWU(l15, kg) * 16 + elb) = pv;
            }
            // scores(h+1): MFMA on prefetched operands, overlaps P DS traffic
            if (h < 2) {
                #pragma unroll
                for (int ut = 0; ut < 4; ++ut)
                    s[nxt][ut] = MFMA(kb[nxt][ut], qaN, bC[ut]);
            }
            // P readback + PV
            const half8 p0 = *(const half8*)(smem + qfr + swbase);
            const half8 p1 = *(const half8*)(smem + plb + swbase);
            #pragma unroll
            for (int nd = 0; nd < 2; ++nd) {
                f4v o = {0.f, 0.f, 0.f, 0.f};
                o = MFMA(nd ? vb10 : vb00, p0, o);
                o = MFMA(nd ? vb11 : vb01, p1, o);
                // ao(h,nd) -> qt[h][w] slot (over dead P-ku0; in-order DS, wave-private)
                uint2 ov;
                ov.x = pkrtz(o[0], o[1]);
                ov.y = pkrtz(o[2], o[3]);
                *(uint2*)(smem + qfr + SWU(l15, nd * 2 + (lg >> 1)) * 16 + elb) = ov;
            }
            if (h < 2) qaC = qaN;
        }
    }
    // NO barrier: phase 3 reads only this wave's own qt slots

    // ============ Phase 3: transposed out-proj, wave w owns m-tile w, dbuf weights ============
    {
        const half8 ob0 = *(const half8*)(smem + QT + ((0 * 4 + w) << 10) + swbase);
        const half8 ob1 = *(const half8*)(smem + QT + ((1 * 4 + w) << 10) + swbase);
        const half8 ob2 = *(const half8*)(smem + QT + ((2 * 4 + w) << 10) + swbase);
        const int t = w * 16 + l15;
        float* obase = nullptr;
        if (t < 49) {
            const int tr = t / 7, tc = t - tr * 7;
            int r = wi7 + tr + 3; if (r >= 224) r -= 224;
            int c = wj7 + tc + 3; if (c >= 224) c -= 224;
            obase = out + ((size_t)((bb * 224 + r) * 224 + c)) * 96;
        }
        half8 wA0, wA1, wA2, wB0, wB1, wB2;
        float4 boA, boB;
        {
            const u16* wp = wo16 + (size_t)l15 * 96 + lg * 8;   // nn = 0
            wA0 = *(const half8*)(wp);
            wA1 = *(const half8*)(wp + 32);
            wA2 = *(const half8*)(wp + 64);
            boA = *(const float4*)(bout + lg * 4);
        }
        #pragma unroll
        for (int nn = 0; nn < 6; ++nn) {
            if (nn < 5) {
                const u16* wp = wo16 + (size_t)((nn + 1) * 16 + l15) * 96 + lg * 8;
                wB0 = *(const half8*)(wp);
                wB1 = *(const half8*)(wp + 32);
                wB2 = *(const half8*)(wp + 64);
                boB = *(const float4*)(bout + (nn + 1) * 16 + lg * 4);
            }
            f4v acc = { boA.x, boA.y, boA.z, boA.w };           // bias as C-operand
            acc = MFMA(wA0, ob0, acc);
            acc = MFMA(wA1, ob1, acc);
            acc = MFMA(wA2, ob2, acc);
            if (obase) {
                float4 res;
                res.x = acc[0]; res.y = acc[1]; res.z = acc[2]; res.w = acc[3];
                *(float4*)(obase + nn * 16 + lg * 4) = res;
            }
            if (nn < 5) { wA0 = wB0; wA1 = wB1; wA2 = wB2; boA = boB; }
        }
    }
}

extern "C" void kernel_launch(void* const* d_in, const int* in_sizes, int n_in,
                              void* d_out, int out_size, void* d_ws, size_t ws_size,
                              hipStream_t stream) {
    const float* x          = (const float*)d_in[0];
    const float* w_qkv      = (const float*)d_in[1];
    const float* b_qkv      = (const float*)d_in[2];
    const float* w_out      = (const float*)d_in[3];
    const float* b_out      = (const float*)d_in[4];
    const float* bias_table = (const float*)d_in[5];
    const int*   rel_index  = (const int*)d_in[6];
    float* outp = (float*)d_out;

    // d_ws: wq16[27648]u16 | wo16[9216]u16 | bmf[3*4*4*256]f32 | bqs[288]f32  (124032 B)
    u16* wq16 = (u16*)d_ws;
    u16* wo16 = wq16 + 27648;
    float* bmf = (float*)((char*)d_ws + 73728);
    float* bqs = (float*)((char*)d_ws + 122880);

    prep_kernel<<<dim3(194), dim3(256), 0, stream>>>(
        w_qkv, w_out, bias_table, rel_index, b_qkv, wq16, wo16, bmf, bqs);
    swin_kernel<<<dim3(8192), dim3(256), 0, stream>>>(
        x, wq16, wo16, bqs, b_out, bmf, outp);
}